// Round 2
// baseline (148.275 us; speedup 1.0000x reference)
//
#include <hip/hip_runtime.h>

// HDC encode + classify, restructured for latency hiding.
// Math: idx = clip(rint(x/20*20),0,20); cnt[b,t,l] = #channels at level l
//       smp[b,t,d] = ts[t,d] * sum_l cnt[b,t,l]*sig[l,d]
//       hv[b,d]    = sum_{j=0}^{124} prod_{i=0}^{3} smp[b,j+i,d-3+i]
//       out[b,k]   = sum_d sign(hv[b,d]) * cw[k,d]
// All intermediates are exact small integers in fp32 -> sign is exact.

#define D_   10000
#define NL_  21
#define B_   4
#define T_   128
#define C_   32
#define NC_  10
#define TD_  50            // output d-columns per tile
#define NT_  200           // tiles per batch (200*50 = 10000)
#define CP_  56            // staged cols: 3 halo + 50 + 3 pad (14 groups of 4)
#define NCG_ 14            // column groups of 4

// ---------- kernel 1: per-(b,t) level histogram -> d_ws ----------
__global__ __launch_bounds__(128)
void hist_kernel(const float* __restrict__ x, float* __restrict__ cnt) {
    __shared__ float h[T_][NL_];
    const int t = threadIdx.x;     // one thread per t, rows are private -> no atomics
    const int b = blockIdx.x;
    #pragma unroll
    for (int l = 0; l < NL_; ++l) h[t][l] = 0.0f;
    const float* xp = x + (b * T_ + t) * C_;
    for (int c = 0; c < C_; ++c) {
        float xv = xp[c];
        float r  = rintf((xv / 20.0f) * 20.0f);   // ref op order; round-half-even
        r = fminf(fmaxf(r, 0.0f), 20.0f);
        h[t][(int)r] += 1.0f;
    }
    float* cp = cnt + (b * T_ + t) * NL_;
    #pragma unroll
    for (int l = 0; l < NL_; ++l) cp[l] = h[t][l];
}

// ---------- kernel 2: fused encode + classify ----------
__global__ __launch_bounds__(256, 3)
void hdc_main(const float* __restrict__ sig,
              const float* __restrict__ ts,
              const float* __restrict__ cw,
              const float* __restrict__ cnt,
              float* __restrict__ out) {
    __shared__ float cnt_s[T_][NL_];   // 10752 B
    __shared__ float smp[T_][CP_];     // 28672 B
    __shared__ float part[5 * TD_];    //  1000 B

    const int tid   = threadIdx.x;
    const int b     = blockIdx.x / NT_;
    const int tile  = blockIdx.x % NT_;
    const int start = tile * TD_;

    // stage counts (coalesced, L2-hot)
    for (int w = tid; w < T_ * NL_; w += 256)
        ((float*)cnt_s)[w] = cnt[b * T_ * NL_ + w];

    // per-thread sig slab in registers: 21 levels x 4 cols
    const int  cg  = tid % NCG_;
    const int  tch = tid / NCG_;        // 0..15 for active threads
    const bool act = tid < (NCG_ * 16); // 224 active
    const int  dd0 = start - 3 + cg * 4;
    float sr[NL_][4];
    if (act) {
        #pragma unroll
        for (int l = 0; l < NL_; ++l) {
            #pragma unroll
            for (int i = 0; i < 4; ++i) {
                int dd = dd0 + i;
                if (dd < 0) dd += D_;
                if (dd >= D_) dd -= D_;
                sr[l][i] = sig[l * D_ + dd];
            }
        }
    }
    __syncthreads();

    // phase 3: smp[t][cg*4..+3] = ts * (cnt . sig), 8 t-rows per thread
    if (act) {
        int d0 = dd0, d1 = dd0 + 1, d2 = dd0 + 2, d3 = dd0 + 3;
        if (d0 < 0) d0 += D_;  if (d0 >= D_) d0 -= D_;
        if (d1 < 0) d1 += D_;  if (d1 >= D_) d1 -= D_;
        if (d2 < 0) d2 += D_;  if (d2 >= D_) d2 -= D_;
        if (d3 < 0) d3 += D_;  if (d3 >= D_) d3 -= D_;
        const int t0 = tch * 8;
        for (int tt = 0; tt < 8; ++tt) {
            const int t = t0 + tt;
            const float* tp = ts + (size_t)t * D_;
            float v0 = tp[d0], v1 = tp[d1], v2 = tp[d2], v3 = tp[d3];
            float a0 = 0.f, a1 = 0.f, a2 = 0.f, a3 = 0.f;
            #pragma unroll
            for (int l = 0; l < NL_; ++l) {
                float cv = cnt_s[t][l];
                a0 += cv * sr[l][0];
                a1 += cv * sr[l][1];
                a2 += cv * sr[l][2];
                a3 += cv * sr[l][3];
            }
            float4 r = make_float4(v0 * a0, v1 * a1, v2 * a2, v3 * a3);
            *(float4*)&smp[t][cg * 4] = r;   // 16B-aligned LDS write
        }
    }
    __syncthreads();

    // phase 4: 4-gram bind + bundle over j, 5 j-chunks per output column
    if (tid < 5 * TD_) {
        const int od = tid % TD_;
        const int jc = tid / TD_;
        const int j0 = jc * 25;
        float acc = 0.0f;
        #pragma unroll 5
        for (int j = j0; j < j0 + 25; ++j) {
            acc += smp[j][od] * smp[j + 1][od + 1] * smp[j + 2][od + 2] * smp[j + 3][od + 3];
        }
        part[tid] = acc;
    }
    __syncthreads();

    // phase 5: sign + classify (wave 0 only; TD_=50 < 64)
    if (tid < 64) {
        float enc = 0.0f;
        if (tid < TD_) {
            float tot = part[tid] + part[tid + TD_] + part[tid + 2 * TD_]
                      + part[tid + 3 * TD_] + part[tid + 4 * TD_];
            enc = (tot > 0.0f) ? 1.0f : -1.0f;   // hard_quantize (==0 -> -1)
        }
        #pragma unroll
        for (int k = 0; k < NC_; ++k) {
            float contrib = (tid < TD_) ? enc * cw[k * D_ + start + tid] : 0.0f;
            #pragma unroll
            for (int m = 32; m >= 1; m >>= 1) contrib += __shfl_xor(contrib, m, 64);
            if (tid == 0) atomicAdd(&out[b * NC_ + k], contrib);
        }
    }
}

extern "C" void kernel_launch(void* const* d_in, const int* in_sizes, int n_in,
                              void* d_out, int out_size, void* d_ws, size_t ws_size,
                              hipStream_t stream) {
    const float* x   = (const float*)d_in[0];
    const float* sig = (const float*)d_in[1];
    // d_in[2] = channels_w: dead bind in the reference, intentionally unused
    const float* ts  = (const float*)d_in[3];
    const float* cw  = (const float*)d_in[4];
    float* out = (float*)d_out;
    float* cnt = (float*)d_ws;   // B*T*NL floats = 10752 B

    hipMemsetAsync(out, 0, (size_t)out_size * sizeof(float), stream);
    hist_kernel<<<B_, T_, 0, stream>>>(x, cnt);
    hdc_main<<<B_ * NT_, 256, 0, stream>>>(sig, ts, cw, cnt, out);
}

// Round 3
// 127.413 us; speedup vs baseline: 1.1637x; 1.1637x over previous
//
#include <hip/hip_runtime.h>

// HDC encode + classify, wave-streaming structure.
// Math: idx = clip(rint(x/20*20),0,20); cnt[b,t,l] = #channels at level l
//       smp[b,t,d] = ts[t,d] * sum_l cnt[b,t,l]*sig[l,d]
//       hv[b,d]    = sum_{j=0}^{124} prod_{i=0}^{3} smp[b,j+i,(d-3+i) mod D]
//       out[b,k]   = sum_d sign(hv[b,d]) * cw[k,d]
// All intermediates are exact small integers in fp32 -> order-free, sign exact.
//
// Structure: lane <-> d-column (coalesced vmem); smp streamed in a 4-deep
// register ring; 4-gram product via shfl_up(3/2/1) from left-neighbor lanes;
// wave covers 61 output columns (3-lane halo); block's 4 waves split the
// j-range 4-way (32/31/31/31 with 3-row overlap), partials merged in LDS.

#define D_     10000
#define NL_    21
#define B_     4
#define T_     128
#define C_     32
#define NC_    10
#define OPW_   61          // output columns per wave (64 lanes - 3 halo)
#define NTILE_ 164         // ceil(D / OPW) ; 164*61 = 10004

// ---------- kernel 1: per-(b,t) level histogram -> d_ws ; also zeroes out ----------
__global__ __launch_bounds__(128)
void hist_kernel(const float* __restrict__ x, float* __restrict__ cnt,
                 float* __restrict__ out) {
    const int t = threadIdx.x;     // one thread per t: rows private -> no atomics
    const int b = blockIdx.x;
    if (b == 0 && t < B_ * NC_) out[t] = 0.0f;
    float h[NL_];
    #pragma unroll
    for (int l = 0; l < NL_; ++l) h[l] = 0.0f;
    const float* xp = x + (b * T_ + t) * C_;
    #pragma unroll 8
    for (int c = 0; c < C_; ++c) {
        float r = rintf((xp[c] / 20.0f) * 20.0f);   // ref op order; round-half-even
        r = fminf(fmaxf(r, 0.0f), 20.0f);
        int lvl = (int)r;
        #pragma unroll
        for (int l = 0; l < NL_; ++l) h[l] += (l == lvl) ? 1.0f : 0.0f;
    }
    float* cp = cnt + (b * T_ + t) * NL_;
    #pragma unroll
    for (int l = 0; l < NL_; ++l) cp[l] = h[l];
}

// ---------- kernel 2: fused encode + classify ----------
__global__ __launch_bounds__(256)
void hdc_main(const float* __restrict__ sig,
              const float* __restrict__ ts,
              const float* __restrict__ cw,
              const float* __restrict__ cnt,
              float* __restrict__ out) {
    __shared__ float hv_s[4][64];

    const int tid  = threadIdx.x;
    const int lane = tid & 63;
    const int w    = tid >> 6;
    const int b    = blockIdx.x / NTILE_;
    const int tile = blockIdx.x % NTILE_;

    int dcol = tile * OPW_ - 3 + lane;          // column this lane streams
    if (dcol < 0)   dcol += D_;                 // roll wrap (tile 0 halo)
    if (dcol >= D_) dcol -= D_;                 // overhang lanes of last tile

    // per-lane signal slab: 21 regs, coalesced 256B/row loads
    float sr[NL_];
    #pragma unroll
    for (int l = 0; l < NL_; ++l) sr[l] = sig[l * D_ + dcol];

    // j-split across the 4 waves: [0,32) [32,63) [63,94) [94,125)
    int jo = (w == 0) ? 0 : (32 + 31 * (w - 1));
    int nj = (w == 0) ? 32 : 31;
    jo = __builtin_amdgcn_readfirstlane(jo);    // make wave-uniform for scalar loads
    nj = __builtin_amdgcn_readfirstlane(nj);

    const float* cb = cnt + (b * T_ + jo) * NL_;   // uniform base
    const float* tp = ts + (size_t)jo * D_ + dcol;

    float a1 = 0.f, a2 = 0.f, a3 = 0.f, hv = 0.f;

    // pipeline fill: t = jo .. jo+2
    #pragma unroll
    for (int it = 0; it < 3; ++it) {
        const float* cr = cb + it * NL_;
        float s0 = 0.f, s1 = 0.f, s2 = 0.f;
        #pragma unroll
        for (int l = 0; l < 7; ++l) {
            s0 += cr[l]      * sr[l];
            s1 += cr[l + 7]  * sr[l + 7];
            s2 += cr[l + 14] * sr[l + 14];
        }
        float a0 = tp[(size_t)it * D_] * ((s0 + s1) + s2);
        a3 = a2; a2 = a1; a1 = a0;
    }
    // main loop: j = jo .. jo+nj-1  (t = j+3)
    #pragma unroll 4
    for (int j = 0; j < nj; ++j) {
        const int it = j + 3;
        const float* cr = cb + it * NL_;
        float s0 = 0.f, s1 = 0.f, s2 = 0.f;
        #pragma unroll
        for (int l = 0; l < 7; ++l) {
            s0 += cr[l]      * sr[l];
            s1 += cr[l + 7]  * sr[l + 7];
            s2 += cr[l + 14] * sr[l + 14];
        }
        float a0 = tp[(size_t)it * D_] * ((s0 + s1) + s2);
        float m3 = __shfl_up(a3, 3);
        float m2 = __shfl_up(a2, 2);
        float m1 = __shfl_up(a1, 1);
        hv += m3 * m2 * m1 * a0;
        a3 = a2; a2 = a1; a1 = a0;
    }

    hv_s[w][lane] = hv;
    __syncthreads();

    // every wave computes the same per-lane total (no broadcast needed)
    float tot = hv_s[0][lane] + hv_s[1][lane] + hv_s[2][lane] + hv_s[3][lane];
    const int  dout  = tile * OPW_ + lane - 3;
    const bool valid = (lane >= 3) && (dout < D_);
    float enc = valid ? ((tot > 0.f) ? 1.f : -1.f) : 0.f;   // hard_quantize

    // classify: wave w handles classes k = w, w+4, w+8
    for (int k = w; k < NC_; k += 4) {
        float contrib = valid ? enc * cw[k * D_ + dout] : 0.f;
        #pragma unroll
        for (int m = 32; m >= 1; m >>= 1) contrib += __shfl_xor(contrib, m, 64);
        if (lane == 0) atomicAdd(&out[b * NC_ + k], contrib);
    }
}

extern "C" void kernel_launch(void* const* d_in, const int* in_sizes, int n_in,
                              void* d_out, int out_size, void* d_ws, size_t ws_size,
                              hipStream_t stream) {
    const float* x   = (const float*)d_in[0];
    const float* sig = (const float*)d_in[1];
    // d_in[2] = channels_w: dead bind in the reference, intentionally unused
    const float* ts  = (const float*)d_in[3];
    const float* cw  = (const float*)d_in[4];
    float* out = (float*)d_out;
    float* cnt = (float*)d_ws;   // B*T*NL floats = 10752 B

    hist_kernel<<<B_, T_, 0, stream>>>(x, cnt, out);
    hdc_main<<<B_ * NTILE_, 256, 0, stream>>>(sig, ts, cw, cnt, out);
}

// Round 4
// 89.056 us; speedup vs baseline: 1.6650x; 1.4307x over previous
//
#include <hip/hip_runtime.h>

// HDC encode + classify, wave-streaming, NO contended global atomics.
// Math: idx = clip(rint(x/20*20),0,20); cnt[b,t,l] = #channels at level l
//       smp[b,t,d] = ts[t,d] * sum_l cnt[b,t,l]*sig[l,d]
//       hv[b,d]    = sum_{j=0}^{124} prod_{i=0}^{3} smp[b,j+i,(d-3+i) mod D]
//       out[b,k]   = sum_d sign(hv[b,d]) * cw[k,d]
// All intermediates are exact small integers in fp32 -> order-free, sign exact.
//
// R3 lesson: 6560 contended atomicAdds to 40 floats (~3 cache lines) cost
// ~10 ns each fully serialized (~60 us). This version stores per-block class
// partials to d_ws (zero contention) and reduces them in a 3rd tiny kernel.

#define D_     10000
#define NL_    21
#define B_     4
#define T_     128
#define C_     32
#define NC_    10
#define OPW_   61          // output columns per wave (64 lanes - 3 halo)
#define NTILE_ 164         // ceil(D / OPW) ; 164*61 = 10004
#define CNT_FLOATS_ (B_ * T_ * NL_)   // 10752

// ---------- kernel 1: per-(b,t) level histogram -> d_ws ----------
__global__ __launch_bounds__(128)
void hist_kernel(const float* __restrict__ x, float* __restrict__ cnt) {
    const int t = threadIdx.x;     // one thread per t: rows private -> no atomics
    const int b = blockIdx.x;
    float h[NL_];
    #pragma unroll
    for (int l = 0; l < NL_; ++l) h[l] = 0.0f;
    const float* xp = x + (b * T_ + t) * C_;
    #pragma unroll 8
    for (int c = 0; c < C_; ++c) {
        float r = rintf((xp[c] / 20.0f) * 20.0f);   // ref op order; round-half-even
        r = fminf(fmaxf(r, 0.0f), 20.0f);
        int lvl = (int)r;
        #pragma unroll
        for (int l = 0; l < NL_; ++l) h[l] += (l == lvl) ? 1.0f : 0.0f;
    }
    float* cp = cnt + (b * T_ + t) * NL_;
    #pragma unroll
    for (int l = 0; l < NL_; ++l) cp[l] = h[l];
}

// ---------- kernel 2: fused encode + classify -> per-block partials ----------
__global__ __launch_bounds__(256)
void hdc_main(const float* __restrict__ sig,
              const float* __restrict__ ts,
              const float* __restrict__ cw,
              const float* __restrict__ cnt,
              float* __restrict__ partial) {
    __shared__ float hv_s[4][64];

    const int tid  = threadIdx.x;
    const int lane = tid & 63;
    const int w    = tid >> 6;
    const int b    = blockIdx.x / NTILE_;
    const int tile = blockIdx.x % NTILE_;

    int dcol = tile * OPW_ - 3 + lane;          // column this lane streams
    if (dcol < 0)   dcol += D_;                 // roll wrap (tile 0 halo)
    if (dcol >= D_) dcol -= D_;                 // overhang lanes of last tile

    // per-lane signal slab: 21 regs, coalesced 256B/row loads
    float sr[NL_];
    #pragma unroll
    for (int l = 0; l < NL_; ++l) sr[l] = sig[l * D_ + dcol];

    // j-split across the 4 waves: [0,32) [32,63) [63,94) [94,125)
    int jo = (w == 0) ? 0 : (32 + 31 * (w - 1));
    int nj = (w == 0) ? 32 : 31;
    jo = __builtin_amdgcn_readfirstlane(jo);    // wave-uniform for scalar loads
    nj = __builtin_amdgcn_readfirstlane(nj);

    const float* cb = cnt + (b * T_ + jo) * NL_;   // uniform base
    const float* tp = ts + (size_t)jo * D_ + dcol;

    float a1 = 0.f, a2 = 0.f, a3 = 0.f, hv = 0.f;

    // pipeline fill: t = jo .. jo+2
    #pragma unroll
    for (int it = 0; it < 3; ++it) {
        const float* cr = cb + it * NL_;
        float s0 = 0.f, s1 = 0.f, s2 = 0.f;
        #pragma unroll
        for (int l = 0; l < 7; ++l) {
            s0 += cr[l]      * sr[l];
            s1 += cr[l + 7]  * sr[l + 7];
            s2 += cr[l + 14] * sr[l + 14];
        }
        float a0 = tp[(size_t)it * D_] * ((s0 + s1) + s2);
        a3 = a2; a2 = a1; a1 = a0;
    }
    // main loop: j = jo .. jo+nj-1  (t = j+3)
    #pragma unroll 4
    for (int j = 0; j < nj; ++j) {
        const int it = j + 3;
        const float* cr = cb + it * NL_;
        float s0 = 0.f, s1 = 0.f, s2 = 0.f;
        #pragma unroll
        for (int l = 0; l < 7; ++l) {
            s0 += cr[l]      * sr[l];
            s1 += cr[l + 7]  * sr[l + 7];
            s2 += cr[l + 14] * sr[l + 14];
        }
        float a0 = tp[(size_t)it * D_] * ((s0 + s1) + s2);
        float m3 = __shfl_up(a3, 3);
        float m2 = __shfl_up(a2, 2);
        float m1 = __shfl_up(a1, 1);
        hv += m3 * m2 * m1 * a0;
        a3 = a2; a2 = a1; a1 = a0;
    }

    hv_s[w][lane] = hv;
    __syncthreads();

    // every wave computes the same per-lane total
    float tot = hv_s[0][lane] + hv_s[1][lane] + hv_s[2][lane] + hv_s[3][lane];
    const int  dout  = tile * OPW_ + lane - 3;
    const bool valid = (lane >= 3) && (dout < D_);
    float enc = valid ? ((tot > 0.f) ? 1.f : -1.f) : 0.f;   // hard_quantize

    // classify: wave w handles classes k = w, w+4, w+8; store partial (no atomics)
    for (int k = w; k < NC_; k += 4) {
        float contrib = valid ? enc * cw[k * D_ + dout] : 0.f;
        #pragma unroll
        for (int m = 32; m >= 1; m >>= 1) contrib += __shfl_xor(contrib, m, 64);
        if (lane == 0) partial[(b * NC_ + k) * NTILE_ + tile] = contrib;
    }
}

// ---------- kernel 3: reduce partials -> out ----------
__global__ __launch_bounds__(64)
void reduce_kernel(const float* __restrict__ partial, float* __restrict__ out) {
    const int row  = blockIdx.x;           // (b*NC + k), 40 rows
    const int lane = threadIdx.x;          // one wave
    const float* rp = partial + row * NTILE_;
    float acc = 0.0f;
    for (int i = lane; i < NTILE_; i += 64) acc += rp[i];
    #pragma unroll
    for (int m = 32; m >= 1; m >>= 1) acc += __shfl_xor(acc, m, 64);
    if (lane == 0) out[row] = acc;
}

extern "C" void kernel_launch(void* const* d_in, const int* in_sizes, int n_in,
                              void* d_out, int out_size, void* d_ws, size_t ws_size,
                              hipStream_t stream) {
    const float* x   = (const float*)d_in[0];
    const float* sig = (const float*)d_in[1];
    // d_in[2] = channels_w: dead bind in the reference, intentionally unused
    const float* ts  = (const float*)d_in[3];
    const float* cw  = (const float*)d_in[4];
    float* out = (float*)d_out;
    float* cnt     = (float*)d_ws;                 // 10752 floats
    float* partial = (float*)d_ws + CNT_FLOATS_;   // 40*164 = 6560 floats

    hist_kernel<<<B_, T_, 0, stream>>>(x, cnt);
    hdc_main<<<B_ * NTILE_, 256, 0, stream>>>(sig, ts, cw, cnt, partial);
    reduce_kernel<<<B_ * NC_, 64, 0, stream>>>(partial, out);
}